// Round 3
// baseline (16513.414 us; speedup 1.0000x reference)
//
#include <hip/hip_runtime.h>
#include <hip/hip_bf16.h>

typedef unsigned short ushort_t;
typedef unsigned int uint_t;
using f32x4 = __attribute__((ext_vector_type(4))) float;
using short8 = __attribute__((ext_vector_type(8))) short;

#define MFMA_B16(a,b,c) __builtin_amdgcn_mfma_f32_16x16x32_bf16((a),(b),(c),0,0,0)

static __device__ __forceinline__ float bf2f(ushort_t u){
  unsigned v = ((unsigned)u) << 16;
  return __builtin_bit_cast(float, v);
}
static __device__ __forceinline__ ushort_t f2bf(float f){
  __hip_bfloat16 h = __float2bfloat16(f);
  return __builtin_bit_cast(unsigned short, h);
}

// ws layout (bf16 elements unless noted):
//   [0, 524288)      : weights, 2048 rows x 256 k (row-major)
//       rows    0- 767 : xproj B  (Wzx^T 0-255, Wrx^T 256-511, Wtx^T 512-767)
//       rows  768-1023 : Wzh^T ; 1024-1279 : Wrh^T ; 1280-1535 : Wth^T ; 1536-2047 : Wd^T
//   [524288, 542208) : aux  (bz|br|btx|bth|bd|h0)
//   byte 1084416     : uint flag (1 = inputs are bf16, 0 = f32)
//   byte 2097152+    : Ax (65536 x 768, bf16)
#define W_ELEMS  524288
#define AUX_OFF  524288
#define AUX_BTH  768
#define AUX_BD   1024
#define AUX_H0   1536
#define FLAG_BYTE 1084416u
#define AX_OFF_BYTES (2u<<20)
#define ROW_ZH 768
#define ROW_RH 1024
#define ROW_TH 1280
#define ROW_D  1536

// ---------------------------------------------------------------- dtype detect
__global__ __launch_bounds__(64) void detect_kernel(const uint_t* __restrict__ x,
                                                    uint_t* __restrict__ flag)
{
  int l = threadIdx.x;
  int cnt = 0;
  for (int i = 0; i < 8; ++i){
    uint_t w = x[i*64 + l];
    uint_t e = (w >> 7) & 0xFF;
    unsigned long long m = __ballot(e >= 100 && e <= 136);
    if (l == 0) cnt += __popcll(m);
  }
  if (l == 0) *flag = (cnt >= 256) ? 1u : 0u;
}

// ---------------------------------------------------------------- prep (canonicalize to bf16)
__global__ __launch_bounds__(256) void prep_kernel(
    const void* __restrict__ Wz, const void* __restrict__ Wr,
    const void* __restrict__ Wtx, const void* __restrict__ Wth,
    const void* __restrict__ Wd,
    const void* __restrict__ bz, const void* __restrict__ br,
    const void* __restrict__ btx, const void* __restrict__ bth,
    const void* __restrict__ bd, const void* __restrict__ h0,
    const uint_t* __restrict__ flag, ushort_t* __restrict__ o)
{
  const bool b16 = (*flag != 0);
  int i = blockIdx.x * 256 + threadIdx.x;          // < 542208
  const void* src; int idx;
  if (i < W_ELEMS){
    int row = i >> 8, k = i & 255;
    if      (row <  256){ src = Wz;  idx = k*256 + row;         }
    else if (row <  512){ src = Wr;  idx = k*256 + (row-256);   }
    else if (row <  768){ src = Wtx; idx = k*256 + (row-512);   }
    else if (row < 1024){ src = Wz;  idx = (256+k)*256 + (row-768);  }
    else if (row < 1280){ src = Wr;  idx = (256+k)*256 + (row-1024); }
    else if (row < 1536){ src = Wth; idx = k*256 + (row-1280);  }
    else                { src = Wd;  idx = k*512 + (row-1536);  }
  } else {
    int j = i - W_ELEMS;
    if      (j <  256){ src = bz;  idx = j;       }
    else if (j <  512){ src = br;  idx = j-256;   }
    else if (j <  768){ src = btx; idx = j-512;   }
    else if (j < 1024){ src = bth; idx = j-768;   }
    else if (j < 1536){ src = bd;  idx = j-1024;  }
    else              { src = h0;  idx = j-1536;  }
  }
  o[i] = b16 ? ((const ushort_t*)src)[idx] : f2bf(((const float*)src)[idx]);
}

// ---------------------------------------------------------------- x projection GEMM
// Ax[m][c] bf16, m = b*1024 + t (65536 rows), c in [0,768)
__global__ __launch_bounds__(256) void xproj_kernel(
    const void* __restrict__ x, const ushort_t* __restrict__ wsB,
    const ushort_t* __restrict__ aux, const uint_t* __restrict__ flag,
    ushort_t* __restrict__ Ax)
{
  __shared__ ushort_t As[32768];               // 128 rows x 256 k, swizzled, 64 KB
  const bool b16 = (*flag != 0);
  const int tid = threadIdx.x, w = tid >> 6, l = tid & 63, lr = l & 15, lg = l >> 4;
  const int mt = blockIdx.x % 512, nb = blockIdx.x / 512;
  const int m0 = mt * 128, n0 = nb * 128;

  #pragma unroll
  for (int i = 0; i < 16; ++i){
    int gidx = i*256 + tid, row = gidx >> 5, g = gidx & 31;
    short8 v;
    if (b16){
      v = *reinterpret_cast<const short8*>((const ushort_t*)x + (m0+row)*256 + g*8);
    } else {
      const f32x4* xf = reinterpret_cast<const f32x4*>((const float*)x + (m0+row)*256 + g*8);
      f32x4 a0 = xf[0], a1 = xf[1];
      v[0]=(short)f2bf(a0[0]); v[1]=(short)f2bf(a0[1]); v[2]=(short)f2bf(a0[2]); v[3]=(short)f2bf(a0[3]);
      v[4]=(short)f2bf(a1[0]); v[5]=(short)f2bf(a1[1]); v[6]=(short)f2bf(a1[2]); v[7]=(short)f2bf(a1[3]);
    }
    *reinterpret_cast<short8*>(reinterpret_cast<char*>(As) + row*512 + ((g ^ (row&7)) << 4)) = v;
  }
  __syncthreads();

  const int wr = w >> 1, wc = w & 1;
  f32x4 acc[4][4];
  #pragma unroll
  for (int a = 0; a < 4; ++a)
    #pragma unroll
    for (int b = 0; b < 4; ++b) acc[a][b] = (f32x4){0.f,0.f,0.f,0.f};

  #pragma unroll
  for (int ks = 0; ks < 8; ++ks){
    short8 av[4], bv[4];
    #pragma unroll
    for (int mi = 0; mi < 4; ++mi){
      int rT = 64*wr + 16*mi + lr, g = ks*4 + lg;
      av[mi] = *reinterpret_cast<const short8*>(reinterpret_cast<const char*>(As) + rT*512 + ((g ^ (rT&7)) << 4));
    }
    #pragma unroll
    for (int ni = 0; ni < 4; ++ni){
      int nr = n0 + 64*wc + 16*ni + lr;
      bv[ni] = *reinterpret_cast<const short8*>(wsB + nr*256 + ks*32 + lg*8);
    }
    #pragma unroll
    for (int mi = 0; mi < 4; ++mi)
      #pragma unroll
      for (int ni = 0; ni < 4; ++ni)
        acc[mi][ni] = MFMA_B16(av[mi], bv[ni], acc[mi][ni]);
  }

  #pragma unroll
  for (int ni = 0; ni < 4; ++ni){
    int c = n0 + 64*wc + 16*ni + lr;
    float bias = bf2f(aux[c]);
    #pragma unroll
    for (int mi = 0; mi < 4; ++mi)
      #pragma unroll
      for (int j = 0; j < 4; ++j){
        int m = m0 + 64*wr + 16*mi + lg*4 + j;
        Ax[m*768 + c] = f2bf(acc[mi][ni][j] + bias);
      }
  }
}

// ---------------------------------------------------------------- recurrent kernel
// 4 WGs x 512 threads (8 waves, 2/SIMD, <=256 VGPR); WG owns 16 batch rows.
// wave w owns cols [32w, 32w+32). LDS: [0,131072) Wth^T swz | h bf16 | h_base bf16
__global__ __launch_bounds__(512, 2) void gru_kernel(
    const ushort_t* __restrict__ ws16, const ushort_t* __restrict__ Ax,
    const void* __restrict__ eps, const uint_t* __restrict__ flag,
    void* __restrict__ outp)
{
  extern __shared__ char smem[];
  const bool b16 = (*flag != 0);
  const ushort_t* e16 = (const ushort_t*)eps;
  const float*    e32 = (const float*)eps;
  ushort_t* o16 = (ushort_t*)outp;
  float*    o32 = (float*)outp;
  const ushort_t* aux = ws16 + AUX_OFF;
  const int tid = threadIdx.x, w = tid >> 6, l = tid & 63, lr = l & 15, lg = l >> 4;
  const int b0 = blockIdx.x * 16;
  const int c0 = 32 * w;

  // stage Wth^T into LDS (swizzled)
  for (int gi = tid; gi < 8192; gi += 512){
    int row = gi >> 5, g = gi & 31;
    short8 v = *reinterpret_cast<const short8*>(ws16 + (ROW_TH + row)*256 + g*8);
    *reinterpret_cast<short8*>(smem + row*512 + ((g ^ (row&7)) << 4)) = v;
  }

  // VGPR-resident B fragments for Wzh, Wrh (128 VGPRs)
  short8 wzh[2][8], wrh[2][8];
  #pragma unroll
  for (int nt = 0; nt < 2; ++nt)
    #pragma unroll
    for (int ks = 0; ks < 8; ++ks){
      wzh[nt][ks] = *reinterpret_cast<const short8*>(ws16 + (ROW_ZH + c0 + 16*nt + lr)*256 + ks*32 + lg*8);
      wrh[nt][ks] = *reinterpret_cast<const short8*>(ws16 + (ROW_RH + c0 + 16*nt + lr)*256 + ks*32 + lg*8);
    }

  float bthv[2], bdm[2], bdl[2];
  #pragma unroll
  for (int nt = 0; nt < 2; ++nt){
    int c = c0 + 16*nt + lr;
    bthv[nt] = bf2f(aux[AUX_BTH + c]);
    bdm[nt]  = bf2f(aux[AUX_BD + c]);
    bdl[nt]  = bf2f(aux[AUX_BD + 256 + c]);
  }

  // h in fp32 regs; lane layout == MFMA C layout (row=lg*4+j, col=c0+16nt+lr)
  float hreg[2][4];
  #pragma unroll
  for (int nt = 0; nt < 2; ++nt)
    #pragma unroll
    for (int j = 0; j < 4; ++j){
      int row = lg*4 + j, c = c0 + 16*nt + lr;
      float hv = bf2f(aux[AUX_H0 + (b0+row)*256 + c]);
      hreg[nt][j] = hv;
      *reinterpret_cast<ushort_t*>(smem + 131072 + row*512 + (((c>>3) ^ (row&7)) << 4) + (c&7)*2) = f2bf(hv);
    }
  __syncthreads();

  const ushort_t* wdB = ws16 + ROW_D*256;
  int prow[4];
  prow[0] = 32*w + lr;
  prow[1] = 32*w + 16 + lr;
  prow[2] = 256 + 32*w + lr;
  prow[3] = 256 + 32*w + 16 + lr;

  for (int t = 0; t < 1024; ++t){
    // this step's global reads (Ax bf16, eps)
    float axz[2][4], axr[2][4], axt[2][4], epsv[2][4];
    #pragma unroll
    for (int nt = 0; nt < 2; ++nt)
      #pragma unroll
      for (int j = 0; j < 4; ++j){
        int bb = b0 + lg*4 + j, c = c0 + 16*nt + lr;
        int mrow = bb*1024 + t;
        const ushort_t* ap = Ax + mrow*768 + c;
        axz[nt][j] = bf2f(ap[0]); axr[nt][j] = bf2f(ap[256]); axt[nt][j] = bf2f(ap[512]);
        int ei = mrow*256 + c;
        epsv[nt][j] = b16 ? bf2f(e16[ei]) : e32[ei];
      }

    // ---- phase 1: z,r,(h@Wth+bth)
    f32x4 az[2], ar[2], at[2];
    #pragma unroll
    for (int nt = 0; nt < 2; ++nt){
      az[nt] = (f32x4){0.f,0.f,0.f,0.f};
      ar[nt] = (f32x4){0.f,0.f,0.f,0.f};
      at[nt] = (f32x4){bthv[nt],bthv[nt],bthv[nt],bthv[nt]};
    }
    #pragma unroll
    for (int ks = 0; ks < 8; ++ks){
      int g = ks*4 + lg;
      short8 a = *reinterpret_cast<const short8*>(smem + 131072 + lr*512 + ((g ^ (lr&7)) << 4));
      int nc0 = c0 + lr, nc1 = c0 + 16 + lr;
      short8 th0 = *reinterpret_cast<const short8*>(smem + nc0*512 + ((g ^ (nc0&7)) << 4));
      short8 th1 = *reinterpret_cast<const short8*>(smem + nc1*512 + ((g ^ (nc1&7)) << 4));
      az[0] = MFMA_B16(a, wzh[0][ks], az[0]);  az[1] = MFMA_B16(a, wzh[1][ks], az[1]);
      ar[0] = MFMA_B16(a, wrh[0][ks], ar[0]);  ar[1] = MFMA_B16(a, wrh[1][ks], ar[1]);
      at[0] = MFMA_B16(a, th0, at[0]);         at[1] = MFMA_B16(a, th1, at[1]);
    }

    // prefetch Wd k-steps 0,1 — stays in flight across the raw barrier (no vmcnt drain)
    short8 wdq[4][2];
    #pragma unroll
    for (int p = 0; p < 4; ++p)
      #pragma unroll
      for (int kk = 0; kk < 2; ++kk)
        wdq[p][kk] = *reinterpret_cast<const short8*>(wdB + prow[p]*256 + kk*32 + lg*8);

    // activations -> h_base (bf16 into LDS)
    #pragma unroll
    for (int nt = 0; nt < 2; ++nt)
      #pragma unroll
      for (int j = 0; j < 4; ++j){
        float zp = az[nt][j] + axz[nt][j];
        float rp = ar[nt][j] + axr[nt][j];
        float zv = 1.f/(1.f + __expf(-zp));
        float rv = 1.f/(1.f + __expf(-rp));
        float tp = axt[nt][j] + rv*at[nt][j];
        float e2 = __expf(-2.f*fabsf(tp));
        float tv = (1.f - e2)/(1.f + e2);
        tv = (tp < 0.f) ? -tv : tv;
        float hb = zv*hreg[nt][j] + (1.f - zv)*tv;
        int row = lg*4 + j, c = c0 + 16*nt + lr;
        *reinterpret_cast<ushort_t*>(smem + 139264 + row*512 + (((c>>3) ^ (row&7)) << 4) + (c&7)*2) = f2bf(hb);
      }
    // barrier 1: order ds_write(h_base) -> ds_read; keep global loads in flight
    asm volatile("s_waitcnt lgkmcnt(0)" ::: "memory");
    __builtin_amdgcn_s_barrier();
    __builtin_amdgcn_sched_barrier(0);

    // ---- phase 2: params = h_base @ Wd + bd (Wd streamed from L2, 2-deep)
    f32x4 ap4[4];
    ap4[0] = (f32x4){bdm[0],bdm[0],bdm[0],bdm[0]};
    ap4[1] = (f32x4){bdm[1],bdm[1],bdm[1],bdm[1]};
    ap4[2] = (f32x4){bdl[0],bdl[0],bdl[0],bdl[0]};
    ap4[3] = (f32x4){bdl[1],bdl[1],bdl[1],bdl[1]};
    #pragma unroll
    for (int ks = 0; ks < 8; ++ks){
      int g = ks*4 + lg;
      short8 a = *reinterpret_cast<const short8*>(smem + 139264 + lr*512 + ((g ^ (lr&7)) << 4));
      short8 w0 = wdq[0][ks&1], w1 = wdq[1][ks&1], w2 = wdq[2][ks&1], w3 = wdq[3][ks&1];
      if (ks < 6){
        #pragma unroll
        for (int p = 0; p < 4; ++p)
          wdq[p][ks&1] = *reinterpret_cast<const short8*>(wdB + prow[p]*256 + (ks+2)*32 + lg*8);
      }
      ap4[0] = MFMA_B16(a, w0, ap4[0]);
      ap4[1] = MFMA_B16(a, w1, ap4[1]);
      ap4[2] = MFMA_B16(a, w2, ap4[2]);
      ap4[3] = MFMA_B16(a, w3, ap4[3]);
    }

    // ---- sample + write h
    #pragma unroll
    for (int nt = 0; nt < 2; ++nt)
      #pragma unroll
      for (int j = 0; j < 4; ++j){
        float mean = fminf(fmaxf(ap4[nt][j], -1000.f), 1000.f);
        float lvv  = fminf(fmaxf(ap4[2+nt][j], -30.f), 30.f);
        float s = mean + __expf(0.5f*lvv)*epsv[nt][j];
        hreg[nt][j] = s;
        int row = lg*4 + j, c = c0 + 16*nt + lr;
        *reinterpret_cast<ushort_t*>(smem + 131072 + row*512 + (((c>>3) ^ (row&7)) << 4) + (c&7)*2) = f2bf(s);
        size_t oi = (size_t)(b0+row)*262144 + (size_t)t*256 + c;
        size_t o2 = 16777216u + (size_t)(b0+row)*256 + c;
        if (b16){
          o16[oi] = f2bf(s);
          if (t == 1023) o16[o2] = f2bf(s);
        } else {
          o32[oi] = s;
          if (t == 1023) o32[o2] = s;
        }
      }
    // barrier 2: order ds_write(h) -> next step's ds_read
    asm volatile("s_waitcnt lgkmcnt(0)" ::: "memory");
    __builtin_amdgcn_s_barrier();
    __builtin_amdgcn_sched_barrier(0);
  }
}

// ---------------------------------------------------------------- host
extern "C" void kernel_launch(void* const* d_in, const int* in_sizes, int n_in,
                              void* d_out, int out_size, void* d_ws, size_t ws_size,
                              hipStream_t stream)
{
  const void* x   = d_in[0];
  const void* h0  = d_in[1];
  const void* eps = d_in[2];
  const void* Wz  = d_in[3];
  const void* bz  = d_in[4];
  const void* Wr  = d_in[5];
  const void* br  = d_in[6];
  const void* Wtx = d_in[7];
  const void* btx = d_in[8];
  const void* Wth = d_in[9];
  const void* bth = d_in[10];
  const void* Wd  = d_in[11];
  const void* bd  = d_in[12];
  ushort_t* ws16 = (ushort_t*)d_ws;
  uint_t* flag = (uint_t*)((char*)d_ws + FLAG_BYTE);
  const ushort_t* aux = ws16 + AUX_OFF;
  ushort_t* Ax = (ushort_t*)((char*)d_ws + AX_OFF_BYTES);

  detect_kernel<<<dim3(1), dim3(64), 0, stream>>>((const uint_t*)x, flag);
  prep_kernel<<<dim3(2118), dim3(256), 0, stream>>>(Wz, Wr, Wtx, Wth, Wd,
                                                    bz, br, btx, bth, bd, h0,
                                                    flag, ws16);
  xproj_kernel<<<dim3(3072), dim3(256), 0, stream>>>(x, ws16, aux, flag, Ax);

  const int SMEM_REC = 147456;
  hipFuncSetAttribute(reinterpret_cast<const void*>(&gru_kernel),
                      hipFuncAttributeMaxDynamicSharedMemorySize, SMEM_REC);
  gru_kernel<<<dim3(4), dim3(512), SMEM_REC, stream>>>(ws16, Ax, eps, flag, d_out);
}

// Round 5
// 14130.627 us; speedup vs baseline: 1.1686x; 1.1686x over previous
//
#include <hip/hip_runtime.h>
#include <hip/hip_bf16.h>

typedef unsigned short ushort_t;
typedef unsigned int uint_t;
using f32x4 = __attribute__((ext_vector_type(4))) float;
using bf4 = __attribute__((ext_vector_type(4))) short;
using short8 = __attribute__((ext_vector_type(8))) short;

#define MFMA_B16(a,b,c) __builtin_amdgcn_mfma_f32_16x16x32_bf16((a),(b),(c),0,0,0)

static __device__ __forceinline__ float bf2f(ushort_t u){
  unsigned v = ((unsigned)u) << 16;
  return __builtin_bit_cast(float, v);
}
static __device__ __forceinline__ ushort_t f2bf(float f){
  __hip_bfloat16 h = __float2bfloat16(f);
  return __builtin_bit_cast(unsigned short, h);
}
static __device__ __forceinline__ f32x4 unpack4(bf4 v){
  f32x4 r;
  r[0]=bf2f((ushort_t)v[0]); r[1]=bf2f((ushort_t)v[1]);
  r[2]=bf2f((ushort_t)v[2]); r[3]=bf2f((ushort_t)v[3]);
  return r;
}

// ws layout:
//   [0, 524288)      : bf16 weights, 2048 rows x 256 k (row-major)
//       rows 0-767: xproj B (Wzx^T|Wrx^T|Wtx^T); 768: Wzh^T; 1024: Wrh^T;
//       1280: Wth^T; 1536-2047: Wd^T
//   [524288, 542208) : bf16 aux (bz|br|btx|bth|bd|h0)
//   byte 1084416     : uint flag (1 = inputs bf16, 0 = f32)
//   byte 2 MB        : Ax bf16 (65536 x 768)
//   byte 112 MB      : eps bf16 (16777216)
#define W_ELEMS  524288
#define AUX_OFF  524288
#define AUX_BTH  768
#define AUX_BD   1024
#define AUX_H0   1536
#define FLAG_BYTE 1084416u
#define AX_OFF_BYTES  (2u<<20)
#define EPS_OFF_BYTES (112u<<20)
#define ROW_ZH 768
#define ROW_RH 1024
#define ROW_TH 1280
#define ROW_D  1536

// ---------------------------------------------------------------- dtype detect
__global__ __launch_bounds__(64) void detect_kernel(const uint_t* __restrict__ x,
                                                    uint_t* __restrict__ flag)
{
  int l = threadIdx.x;
  int cnt = 0;
  for (int i = 0; i < 8; ++i){
    uint_t w = x[i*64 + l];
    uint_t e = (w >> 7) & 0xFF;
    unsigned long long m = __ballot(e >= 100 && e <= 136);
    if (l == 0) cnt += __popcll(m);
  }
  if (l == 0) *flag = (cnt >= 256) ? 1u : 0u;
}

// ---------------------------------------------------------------- prep (canonicalize to bf16)
__global__ __launch_bounds__(256) void prep_kernel(
    const void* __restrict__ Wz, const void* __restrict__ Wr,
    const void* __restrict__ Wtx, const void* __restrict__ Wth,
    const void* __restrict__ Wd,
    const void* __restrict__ bz, const void* __restrict__ br,
    const void* __restrict__ btx, const void* __restrict__ bth,
    const void* __restrict__ bd, const void* __restrict__ h0,
    const uint_t* __restrict__ flag, ushort_t* __restrict__ o)
{
  const bool b16 = (*flag != 0);
  int i = blockIdx.x * 256 + threadIdx.x;          // < 542208
  const void* src; int idx;
  if (i < W_ELEMS){
    int row = i >> 8, k = i & 255;
    if      (row <  256){ src = Wz;  idx = k*256 + row;         }
    else if (row <  512){ src = Wr;  idx = k*256 + (row-256);   }
    else if (row <  768){ src = Wtx; idx = k*256 + (row-512);   }
    else if (row < 1024){ src = Wz;  idx = (256+k)*256 + (row-768);  }
    else if (row < 1280){ src = Wr;  idx = (256+k)*256 + (row-1024); }
    else if (row < 1536){ src = Wth; idx = k*256 + (row-1280);  }
    else                { src = Wd;  idx = k*512 + (row-1536);  }
  } else {
    int j = i - W_ELEMS;
    if      (j <  256){ src = bz;  idx = j;       }
    else if (j <  512){ src = br;  idx = j-256;   }
    else if (j <  768){ src = btx; idx = j-512;   }
    else if (j < 1024){ src = bth; idx = j-768;   }
    else if (j < 1536){ src = bd;  idx = j-1024;  }
    else              { src = h0;  idx = j-1536;  }
  }
  o[i] = b16 ? ((const ushort_t*)src)[idx] : f2bf(((const float*)src)[idx]);
}

// ---------------------------------------------------------------- eps -> bf16
__global__ __launch_bounds__(256) void epscvt_kernel(
    const void* __restrict__ eps, const uint_t* __restrict__ flag,
    ushort_t* __restrict__ o)
{
  const bool b16 = (*flag != 0);
  int i = blockIdx.x * 256 + threadIdx.x;          // 8 elems each, 16777216 total
  if (b16){
    short8 v = reinterpret_cast<const short8*>(eps)[i];
    reinterpret_cast<short8*>(o)[i] = v;
  } else {
    const f32x4* e = reinterpret_cast<const f32x4*>(eps) + i*2;
    f32x4 a = e[0], b = e[1];
    short8 v;
    v[0]=(short)f2bf(a[0]); v[1]=(short)f2bf(a[1]); v[2]=(short)f2bf(a[2]); v[3]=(short)f2bf(a[3]);
    v[4]=(short)f2bf(b[0]); v[5]=(short)f2bf(b[1]); v[6]=(short)f2bf(b[2]); v[7]=(short)f2bf(b[3]);
    reinterpret_cast<short8*>(o)[i] = v;
  }
}

// ---------------------------------------------------------------- x projection GEMM
__global__ __launch_bounds__(256) void xproj_kernel(
    const void* __restrict__ x, const ushort_t* __restrict__ wsB,
    const ushort_t* __restrict__ aux, const uint_t* __restrict__ flag,
    ushort_t* __restrict__ Ax)
{
  __shared__ ushort_t As[32768];
  const bool b16 = (*flag != 0);
  const int tid = threadIdx.x, w = tid >> 6, l = tid & 63, lr = l & 15, lg = l >> 4;
  const int mt = blockIdx.x % 512, nb = blockIdx.x / 512;
  const int m0 = mt * 128, n0 = nb * 128;

  #pragma unroll
  for (int i = 0; i < 16; ++i){
    int gidx = i*256 + tid, row = gidx >> 5, g = gidx & 31;
    short8 v;
    if (b16){
      v = *reinterpret_cast<const short8*>((const ushort_t*)x + (m0+row)*256 + g*8);
    } else {
      const f32x4* xf = reinterpret_cast<const f32x4*>((const float*)x + (m0+row)*256 + g*8);
      f32x4 a0 = xf[0], a1 = xf[1];
      v[0]=(short)f2bf(a0[0]); v[1]=(short)f2bf(a0[1]); v[2]=(short)f2bf(a0[2]); v[3]=(short)f2bf(a0[3]);
      v[4]=(short)f2bf(a1[0]); v[5]=(short)f2bf(a1[1]); v[6]=(short)f2bf(a1[2]); v[7]=(short)f2bf(a1[3]);
    }
    *reinterpret_cast<short8*>(reinterpret_cast<char*>(As) + row*512 + ((g ^ (row&7)) << 4)) = v;
  }
  __syncthreads();

  const int wr = w >> 1, wc = w & 1;
  f32x4 acc[4][4];
  #pragma unroll
  for (int a = 0; a < 4; ++a)
    #pragma unroll
    for (int b = 0; b < 4; ++b) acc[a][b] = (f32x4){0.f,0.f,0.f,0.f};

  #pragma unroll
  for (int ks = 0; ks < 8; ++ks){
    short8 av[4], bv[4];
    #pragma unroll
    for (int mi = 0; mi < 4; ++mi){
      int rT = 64*wr + 16*mi + lr, g = ks*4 + lg;
      av[mi] = *reinterpret_cast<const short8*>(reinterpret_cast<const char*>(As) + rT*512 + ((g ^ (rT&7)) << 4));
    }
    #pragma unroll
    for (int ni = 0; ni < 4; ++ni){
      int nr = n0 + 64*wc + 16*ni + lr;
      bv[ni] = *reinterpret_cast<const short8*>(wsB + nr*256 + ks*32 + lg*8);
    }
    #pragma unroll
    for (int mi = 0; mi < 4; ++mi)
      #pragma unroll
      for (int ni = 0; ni < 4; ++ni)
        acc[mi][ni] = MFMA_B16(av[mi], bv[ni], acc[mi][ni]);
  }

  #pragma unroll
  for (int ni = 0; ni < 4; ++ni){
    int c = n0 + 64*wc + 16*ni + lr;
    float bias = bf2f(aux[c]);
    #pragma unroll
    for (int mi = 0; mi < 4; ++mi)
      #pragma unroll
      for (int j = 0; j < 4; ++j){
        int m = m0 + 64*wr + 16*mi + lg*4 + j;
        Ax[m*768 + c] = f2bf(acc[mi][ni][j] + bias);
      }
  }
}

// ---------------------------------------------------------------- recurrent kernel
// 4 WGs x 512 threads (8 waves, pinned 2/SIMD -> 256 VGPR budget).
// WG owns batch rows [16*bid, +16); wave w owns cols [32w, 32w+32).
// MFMA operand-swapped: D = W_frag(A) * h_frag(B); C-layout: lane holds
// (batch = lane&15, cols = c0+16nt + (lane>>4)*4 + q).
// LDS: [0,131072) Wth^T swz | [131072,+8192) h bf16 | [139264,+8192) h_base
__global__ __attribute__((amdgpu_waves_per_eu(2,2))) __launch_bounds__(512)
void gru_kernel(
    const ushort_t* __restrict__ ws16, const ushort_t* __restrict__ Ax,
    const ushort_t* __restrict__ eps16, const uint_t* __restrict__ flag,
    void* __restrict__ outp)
{
  extern __shared__ char smem[];
  const bool b16 = (*flag != 0);
  ushort_t* o16 = (ushort_t*)outp;
  float*    o32 = (float*)outp;
  const ushort_t* aux = ws16 + AUX_OFF;
  const int tid = threadIdx.x, w = tid >> 6, l = tid & 63, lr = l & 15, lg = l >> 4;
  const int b0 = blockIdx.x * 16;
  const int c0 = 32 * w;
  const int cl = c0 + lg*4;                 // this lane's col base within nt=0 tile

  // stage Wth^T into LDS (swizzled)
  for (int gi = tid; gi < 8192; gi += 512){
    int row = gi >> 5, g = gi & 31;
    short8 v = *reinterpret_cast<const short8*>(ws16 + (ROW_TH + row)*256 + g*8);
    *reinterpret_cast<short8*>(smem + row*512 + ((g ^ (row&7)) << 4)) = v;
  }

  // VGPR-resident A fragments for Wzh, Wrh (rows = output cols, 128 VGPRs)
  short8 wzh[2][8], wrh[2][8];
  #pragma unroll
  for (int nt = 0; nt < 2; ++nt)
    #pragma unroll
    for (int ks = 0; ks < 8; ++ks){
      wzh[nt][ks] = *reinterpret_cast<const short8*>(ws16 + (ROW_ZH + c0 + 16*nt + lr)*256 + ks*32 + lg*8);
      wrh[nt][ks] = *reinterpret_cast<const short8*>(ws16 + (ROW_RH + c0 + 16*nt + lr)*256 + ks*32 + lg*8);
    }

  // biases at this lane's 4 consecutive cols per nt
  f32x4 bthv[2], bdm[2], bdl[2];
  #pragma unroll
  for (int nt = 0; nt < 2; ++nt){
    int c = cl + 16*nt;
    bthv[nt] = unpack4(*reinterpret_cast<const bf4*>(aux + AUX_BTH + c));
    bdm[nt]  = unpack4(*reinterpret_cast<const bf4*>(aux + AUX_BD + c));
    bdl[nt]  = unpack4(*reinterpret_cast<const bf4*>(aux + AUX_BD + 256 + c));
  }

  // h in fp32 regs; lane holds (batch=lr, cols cl+16nt+q)
  f32x4 hreg[2];
  #pragma unroll
  for (int nt = 0; nt < 2; ++nt){
    int c = cl + 16*nt;
    hreg[nt] = unpack4(*reinterpret_cast<const bf4*>(aux + AUX_H0 + (b0+lr)*256 + c));
    bf4 hv;
    hv[0]=(short)f2bf(hreg[nt][0]); hv[1]=(short)f2bf(hreg[nt][1]);
    hv[2]=(short)f2bf(hreg[nt][2]); hv[3]=(short)f2bf(hreg[nt][3]);
    *reinterpret_cast<bf4*>(smem + 131072 + lr*512 + (((c>>3) ^ (lr&7)) << 4) + (c&7)*2) = hv;
  }
  __syncthreads();

  const ushort_t* wdB = ws16 + ROW_D*256;

  for (int t = 0; t < 1024; ++t){
    // batched loads: 4-contiguous per lane (b64 each)
    f32x4 axz[2], axr[2], axt[2], epsv[2];
    {
      const ushort_t* ap = Ax + ((size_t)(b0+lr)*1024 + t)*768 + cl;
      const ushort_t* ep = eps16 + ((size_t)(b0+lr)*1024 + t)*256 + cl;
      #pragma unroll
      for (int nt = 0; nt < 2; ++nt){
        axz[nt] = unpack4(*reinterpret_cast<const bf4*>(ap + 16*nt));
        axr[nt] = unpack4(*reinterpret_cast<const bf4*>(ap + 256 + 16*nt));
        axt[nt] = unpack4(*reinterpret_cast<const bf4*>(ap + 512 + 16*nt));
        epsv[nt] = unpack4(*reinterpret_cast<const bf4*>(ep + 16*nt));
      }
    }

    // ---- phase 1: z,r,(h@Wth+bth); D = W(A) x h(B)
    f32x4 az[2], ar[2], at[2];
    az[0] = (f32x4){0.f,0.f,0.f,0.f}; az[1] = az[0];
    ar[0] = az[0]; ar[1] = az[0];
    at[0] = bthv[0]; at[1] = bthv[1];
    #pragma unroll
    for (int ks = 0; ks < 8; ++ks){
      int g = ks*4 + lg;
      short8 h = *reinterpret_cast<const short8*>(smem + 131072 + lr*512 + ((g ^ (lr&7)) << 4));
      int nc0 = c0 + lr, nc1 = c0 + 16 + lr;
      short8 th0 = *reinterpret_cast<const short8*>(smem + nc0*512 + ((g ^ (nc0&7)) << 4));
      short8 th1 = *reinterpret_cast<const short8*>(smem + nc1*512 + ((g ^ (nc1&7)) << 4));
      az[0] = MFMA_B16(wzh[0][ks], h, az[0]);  az[1] = MFMA_B16(wzh[1][ks], h, az[1]);
      ar[0] = MFMA_B16(wrh[0][ks], h, ar[0]);  ar[1] = MFMA_B16(wrh[1][ks], h, ar[1]);
      at[0] = MFMA_B16(th0, h, at[0]);         at[1] = MFMA_B16(th1, h, at[1]);
    }

    // prefetch Wd k-steps 0,1 (A rows = param cols; in flight across barrier)
    short8 wdq[4][2];
    #pragma unroll
    for (int p = 0; p < 4; ++p){
      int pr = ((p&1) ? 256 : 0) + c0 + ((p>>1) ? 16 : 0) + lr;   // p: m0,l0,m1,l1
      #pragma unroll
      for (int kk = 0; kk < 2; ++kk)
        wdq[p][kk] = *reinterpret_cast<const short8*>(wdB + pr*256 + kk*32 + lg*8);
    }

    // activations -> h_base (packed b64 into LDS, conflict-free)
    #pragma unroll
    for (int nt = 0; nt < 2; ++nt){
      bf4 hb4;
      #pragma unroll
      for (int q = 0; q < 4; ++q){
        float zp = az[nt][q] + axz[nt][q];
        float rp = ar[nt][q] + axr[nt][q];
        float zv = 1.f/(1.f + __expf(-zp));
        float rv = 1.f/(1.f + __expf(-rp));
        float tp = axt[nt][q] + rv*at[nt][q];
        float e2 = __expf(-2.f*fabsf(tp));
        float tv = (1.f - e2)/(1.f + e2);
        tv = (tp < 0.f) ? -tv : tv;
        float hb = zv*hreg[nt][q] + (1.f - zv)*tv;
        hb4[q] = (short)f2bf(hb);
      }
      int c = cl + 16*nt;
      *reinterpret_cast<bf4*>(smem + 139264 + lr*512 + (((c>>3) ^ (lr&7)) << 4) + (c&7)*2) = hb4;
    }
    asm volatile("s_waitcnt lgkmcnt(0)" ::: "memory");
    __builtin_amdgcn_s_barrier();
    asm volatile("" ::: "memory");

    // ---- phase 2: params = h_base @ Wd + bd (Wd streamed from L2, 2-deep)
    f32x4 ap4[4];
    ap4[0] = bdm[0]; ap4[1] = bdl[0]; ap4[2] = bdm[1]; ap4[3] = bdl[1];
    #pragma unroll
    for (int ks = 0; ks < 8; ++ks){
      int g = ks*4 + lg;
      short8 hb = *reinterpret_cast<const short8*>(smem + 139264 + lr*512 + ((g ^ (lr&7)) << 4));
      short8 w0 = wdq[0][ks&1], w1 = wdq[1][ks&1], w2 = wdq[2][ks&1], w3 = wdq[3][ks&1];
      if (ks < 6){
        #pragma unroll
        for (int p = 0; p < 4; ++p){
          int pr = ((p&1) ? 256 : 0) + c0 + ((p>>1) ? 16 : 0) + lr;
          wdq[p][ks&1] = *reinterpret_cast<const short8*>(wdB + pr*256 + (ks+2)*32 + lg*8);
        }
      }
      ap4[0] = MFMA_B16(w0, hb, ap4[0]);
      ap4[1] = MFMA_B16(w1, hb, ap4[1]);
      ap4[2] = MFMA_B16(w2, hb, ap4[2]);
      ap4[3] = MFMA_B16(w3, hb, ap4[3]);
    }

    // ---- sample + write h (lane holds batch=lr, 4 consecutive cols per nt)
    #pragma unroll
    for (int nt = 0; nt < 2; ++nt){
      bf4 s4;
      f32x4 sf;
      #pragma unroll
      for (int q = 0; q < 4; ++q){
        float mean = fminf(fmaxf(ap4[2*nt][q],   -1000.f), 1000.f);
        float lvv  = fminf(fmaxf(ap4[2*nt+1][q], -30.f),   30.f);
        float s = mean + __expf(0.5f*lvv)*epsv[nt][q];
        hreg[nt][q] = s;
        sf[q] = s;
        s4[q] = (short)f2bf(s);
      }
      int c = cl + 16*nt;
      *reinterpret_cast<bf4*>(smem + 131072 + lr*512 + (((c>>3) ^ (lr&7)) << 4) + (c&7)*2) = s4;
      size_t oi = (size_t)(b0+lr)*262144 + (size_t)t*256 + c;
      size_t o2 = 16777216u + (size_t)(b0+lr)*256 + c;
      if (b16){
        *reinterpret_cast<bf4*>(o16 + oi) = s4;
        if (t == 1023) *reinterpret_cast<bf4*>(o16 + o2) = s4;
      } else {
        *reinterpret_cast<f32x4*>(o32 + oi) = sf;
        if (t == 1023) *reinterpret_cast<f32x4*>(o32 + o2) = sf;
      }
    }
    asm volatile("s_waitcnt lgkmcnt(0)" ::: "memory");
    __builtin_amdgcn_s_barrier();
    asm volatile("" ::: "memory");
  }
}

// ---------------------------------------------------------------- host
extern "C" void kernel_launch(void* const* d_in, const int* in_sizes, int n_in,
                              void* d_out, int out_size, void* d_ws, size_t ws_size,
                              hipStream_t stream)
{
  const void* x   = d_in[0];
  const void* h0  = d_in[1];
  const void* eps = d_in[2];
  const void* Wz  = d_in[3];
  const void* bz  = d_in[4];
  const void* Wr  = d_in[5];
  const void* br  = d_in[6];
  const void* Wtx = d_in[7];
  const void* btx = d_in[8];
  const void* Wth = d_in[9];
  const void* bth = d_in[10];
  const void* Wd  = d_in[11];
  const void* bd  = d_in[12];
  ushort_t* ws16 = (ushort_t*)d_ws;
  uint_t* flag = (uint_t*)((char*)d_ws + FLAG_BYTE);
  const ushort_t* aux = ws16 + AUX_OFF;
  ushort_t* Ax = (ushort_t*)((char*)d_ws + AX_OFF_BYTES);
  ushort_t* eps16 = (ushort_t*)((char*)d_ws + EPS_OFF_BYTES);

  detect_kernel<<<dim3(1), dim3(64), 0, stream>>>((const uint_t*)x, flag);
  prep_kernel<<<dim3(2118), dim3(256), 0, stream>>>(Wz, Wr, Wtx, Wth, Wd,
                                                    bz, br, btx, bth, bd, h0,
                                                    flag, ws16);
  epscvt_kernel<<<dim3(8192), dim3(256), 0, stream>>>(eps, flag, eps16);
  xproj_kernel<<<dim3(3072), dim3(256), 0, stream>>>(x, ws16, aux, flag, Ax);

  const int SMEM_REC = 147456;
  (void)hipFuncSetAttribute(reinterpret_cast<const void*>(&gru_kernel),
                            hipFuncAttributeMaxDynamicSharedMemorySize, SMEM_REC);
  gru_kernel<<<dim3(4), dim3(512), SMEM_REC, stream>>>(ws16, Ax, eps16, flag, d_out);
}

// Round 6
// 11060.036 us; speedup vs baseline: 1.4931x; 1.2776x over previous
//
#include <hip/hip_runtime.h>
#include <hip/hip_bf16.h>

typedef unsigned short ushort_t;
typedef unsigned int uint_t;
using f32x4 = __attribute__((ext_vector_type(4))) float;
using bf4 = __attribute__((ext_vector_type(4))) short;
using short8 = __attribute__((ext_vector_type(8))) short;

#define MFMA_B16(a,b,c) __builtin_amdgcn_mfma_f32_16x16x32_bf16((a),(b),(c),0,0,0)

static __device__ __forceinline__ float bf2f(ushort_t u){
  unsigned v = ((unsigned)u) << 16;
  return __builtin_bit_cast(float, v);
}
static __device__ __forceinline__ ushort_t f2bf(float f){
  __hip_bfloat16 h = __float2bfloat16(f);
  return __builtin_bit_cast(unsigned short, h);
}
static __device__ __forceinline__ f32x4 unpack4(bf4 v){
  f32x4 r;
  r[0]=bf2f((ushort_t)v[0]); r[1]=bf2f((ushort_t)v[1]);
  r[2]=bf2f((ushort_t)v[2]); r[3]=bf2f((ushort_t)v[3]);
  return r;
}

// ws layout:
//   [0, 524288)      : bf16 weights, 2048 rows x 256 k (row-major)
//       rows 0-767: xproj B (Wzx^T|Wrx^T|Wtx^T); 768: Wzh^T; 1024: Wrh^T;
//       1280: Wth^T; 1536-2047: Wd^T
//   [524288, 542208) : bf16 aux (bz|br|btx|bth|bd|h0)
//   byte 1084416     : uint flag (1 = inputs bf16, 0 = f32)
//   byte 2 MB        : Ax bf16 (65536 x 768)
//   byte 112 MB      : eps bf16 (16777216)
#define W_ELEMS  524288
#define AUX_OFF  524288
#define AUX_BTH  768
#define AUX_BD   1024
#define AUX_H0   1536
#define FLAG_BYTE 1084416u
#define AX_OFF_BYTES  (2u<<20)
#define EPS_OFF_BYTES (112u<<20)
#define ROW_ZH 768
#define ROW_RH 1024
#define ROW_TH 1280
#define ROW_D  1536

// ---------------------------------------------------------------- dtype detect
__global__ __launch_bounds__(64) void detect_kernel(const uint_t* __restrict__ x,
                                                    uint_t* __restrict__ flag)
{
  int l = threadIdx.x;
  int cnt = 0;
  for (int i = 0; i < 8; ++i){
    uint_t w = x[i*64 + l];
    uint_t e = (w >> 7) & 0xFF;
    unsigned long long m = __ballot(e >= 100 && e <= 136);
    if (l == 0) cnt += __popcll(m);
  }
  if (l == 0) *flag = (cnt >= 256) ? 1u : 0u;
}

// ---------------------------------------------------------------- prep (canonicalize to bf16)
__global__ __launch_bounds__(256) void prep_kernel(
    const void* __restrict__ Wz, const void* __restrict__ Wr,
    const void* __restrict__ Wtx, const void* __restrict__ Wth,
    const void* __restrict__ Wd,
    const void* __restrict__ bz, const void* __restrict__ br,
    const void* __restrict__ btx, const void* __restrict__ bth,
    const void* __restrict__ bd, const void* __restrict__ h0,
    const uint_t* __restrict__ flag, ushort_t* __restrict__ o)
{
  const bool b16 = (*flag != 0);
  int i = blockIdx.x * 256 + threadIdx.x;          // < 542208
  const void* src; int idx;
  if (i < W_ELEMS){
    int row = i >> 8, k = i & 255;
    if      (row <  256){ src = Wz;  idx = k*256 + row;         }
    else if (row <  512){ src = Wr;  idx = k*256 + (row-256);   }
    else if (row <  768){ src = Wtx; idx = k*256 + (row-512);   }
    else if (row < 1024){ src = Wz;  idx = (256+k)*256 + (row-768);  }
    else if (row < 1280){ src = Wr;  idx = (256+k)*256 + (row-1024); }
    else if (row < 1536){ src = Wth; idx = k*256 + (row-1280);  }
    else                { src = Wd;  idx = k*512 + (row-1536);  }
  } else {
    int j = i - W_ELEMS;
    if      (j <  256){ src = bz;  idx = j;       }
    else if (j <  512){ src = br;  idx = j-256;   }
    else if (j <  768){ src = btx; idx = j-512;   }
    else if (j < 1024){ src = bth; idx = j-768;   }
    else if (j < 1536){ src = bd;  idx = j-1024;  }
    else              { src = h0;  idx = j-1536;  }
  }
  o[i] = b16 ? ((const ushort_t*)src)[idx] : f2bf(((const float*)src)[idx]);
}

// ---------------------------------------------------------------- eps -> bf16
__global__ __launch_bounds__(256) void epscvt_kernel(
    const void* __restrict__ eps, const uint_t* __restrict__ flag,
    ushort_t* __restrict__ o)
{
  const bool b16 = (*flag != 0);
  int i = blockIdx.x * 256 + threadIdx.x;          // 8 elems each, 16777216 total
  if (b16){
    short8 v = reinterpret_cast<const short8*>(eps)[i];
    reinterpret_cast<short8*>(o)[i] = v;
  } else {
    const f32x4* e = reinterpret_cast<const f32x4*>(eps) + i*2;
    f32x4 a = e[0], b = e[1];
    short8 v;
    v[0]=(short)f2bf(a[0]); v[1]=(short)f2bf(a[1]); v[2]=(short)f2bf(a[2]); v[3]=(short)f2bf(a[3]);
    v[4]=(short)f2bf(b[0]); v[5]=(short)f2bf(b[1]); v[6]=(short)f2bf(b[2]); v[7]=(short)f2bf(b[3]);
    reinterpret_cast<short8*>(o)[i] = v;
  }
}

// ---------------------------------------------------------------- x projection GEMM
__global__ __launch_bounds__(256) void xproj_kernel(
    const void* __restrict__ x, const ushort_t* __restrict__ wsB,
    const ushort_t* __restrict__ aux, const uint_t* __restrict__ flag,
    ushort_t* __restrict__ Ax)
{
  __shared__ ushort_t As[32768];
  const bool b16 = (*flag != 0);
  const int tid = threadIdx.x, w = tid >> 6, l = tid & 63, lr = l & 15, lg = l >> 4;
  const int mt = blockIdx.x % 512, nb = blockIdx.x / 512;
  const int m0 = mt * 128, n0 = nb * 128;

  #pragma unroll
  for (int i = 0; i < 16; ++i){
    int gidx = i*256 + tid, row = gidx >> 5, g = gidx & 31;
    short8 v;
    if (b16){
      v = *reinterpret_cast<const short8*>((const ushort_t*)x + (m0+row)*256 + g*8);
    } else {
      const f32x4* xf = reinterpret_cast<const f32x4*>((const float*)x + (m0+row)*256 + g*8);
      f32x4 a0 = xf[0], a1 = xf[1];
      v[0]=(short)f2bf(a0[0]); v[1]=(short)f2bf(a0[1]); v[2]=(short)f2bf(a0[2]); v[3]=(short)f2bf(a0[3]);
      v[4]=(short)f2bf(a1[0]); v[5]=(short)f2bf(a1[1]); v[6]=(short)f2bf(a1[2]); v[7]=(short)f2bf(a1[3]);
    }
    *reinterpret_cast<short8*>(reinterpret_cast<char*>(As) + row*512 + ((g ^ (row&7)) << 4)) = v;
  }
  __syncthreads();

  const int wr = w >> 1, wc = w & 1;
  f32x4 acc[4][4];
  #pragma unroll
  for (int a = 0; a < 4; ++a)
    #pragma unroll
    for (int b = 0; b < 4; ++b) acc[a][b] = (f32x4){0.f,0.f,0.f,0.f};

  #pragma unroll
  for (int ks = 0; ks < 8; ++ks){
    short8 av[4], bv[4];
    #pragma unroll
    for (int mi = 0; mi < 4; ++mi){
      int rT = 64*wr + 16*mi + lr, g = ks*4 + lg;
      av[mi] = *reinterpret_cast<const short8*>(reinterpret_cast<const char*>(As) + rT*512 + ((g ^ (rT&7)) << 4));
    }
    #pragma unroll
    for (int ni = 0; ni < 4; ++ni){
      int nr = n0 + 64*wc + 16*ni + lr;
      bv[ni] = *reinterpret_cast<const short8*>(wsB + nr*256 + ks*32 + lg*8);
    }
    #pragma unroll
    for (int mi = 0; mi < 4; ++mi)
      #pragma unroll
      for (int ni = 0; ni < 4; ++ni)
        acc[mi][ni] = MFMA_B16(av[mi], bv[ni], acc[mi][ni]);
  }

  #pragma unroll
  for (int ni = 0; ni < 4; ++ni){
    int c = n0 + 64*wc + 16*ni + lr;
    float bias = bf2f(aux[c]);
    #pragma unroll
    for (int mi = 0; mi < 4; ++mi)
      #pragma unroll
      for (int j = 0; j < 4; ++j){
        int m = m0 + 64*wr + 16*mi + lg*4 + j;
        Ax[m*768 + c] = f2bf(acc[mi][ni][j] + bias);
      }
  }
}

// ---------------------------------------------------------------- recurrent kernel
// 4 WGs x 512 threads (8 waves, 1 WG/CU by LDS -> 2 waves/SIMD; VGPR budget
// pinned to 256 via amdgpu_num_vgpr). WG owns batch rows [16*bid, +16);
// wave w owns cols [32w, 32w+32). MFMA operand-swapped: D = W(A) x h(B);
// lane holds (batch = lane&15, cols = 32w + 16nt + (lane>>4)*4 + q).
// LDS: [0,131072) Wth^T swz | +8192 h | +8192 h_base | +1536 biases(bth|bd)
__global__ __attribute__((amdgpu_flat_work_group_size(512, 512),
                          amdgpu_waves_per_eu(2, 2), amdgpu_num_vgpr(256)))
void gru_kernel(
    const ushort_t* __restrict__ ws16, const ushort_t* __restrict__ Ax,
    const ushort_t* __restrict__ eps16, const uint_t* __restrict__ flag,
    void* __restrict__ outp)
{
  extern __shared__ char smem[];
  const bool b16 = (*flag != 0);
  ushort_t* o16 = (ushort_t*)outp;
  float*    o32 = (float*)outp;
  const ushort_t* aux = ws16 + AUX_OFF;
  ushort_t* bias_lds = (ushort_t*)(smem + 147456);   // bth[256] | bd[512]
  const int tid = threadIdx.x, w = tid >> 6, l = tid & 63, lr = l & 15, lg = l >> 4;
  const int b0 = blockIdx.x * 16;
  const int c0 = 32 * w;
  const int cl = c0 + lg*4;                 // lane's col base (nt=0)

  // stage Wth^T into LDS (swizzled) + biases
  for (int gi = tid; gi < 8192; gi += 512){
    int row = gi >> 5, g = gi & 31;
    short8 v = *reinterpret_cast<const short8*>(ws16 + (ROW_TH + row)*256 + g*8);
    *reinterpret_cast<short8*>(smem + row*512 + ((g ^ (row&7)) << 4)) = v;
  }
  if (tid < 256) bias_lds[tid] = aux[AUX_BTH + tid];
  if (tid < 512) bias_lds[256 + tid] = aux[AUX_BD + tid];

  // VGPR-resident A fragments for Wzh, Wrh (128 VGPRs)
  short8 wzh[2][8], wrh[2][8];
  #pragma unroll
  for (int nt = 0; nt < 2; ++nt)
    #pragma unroll
    for (int ks = 0; ks < 8; ++ks){
      wzh[nt][ks] = *reinterpret_cast<const short8*>(ws16 + (ROW_ZH + c0 + 16*nt + lr)*256 + ks*32 + lg*8);
      wrh[nt][ks] = *reinterpret_cast<const short8*>(ws16 + (ROW_RH + c0 + 16*nt + lr)*256 + ks*32 + lg*8);
    }

  // h in fp32 regs; lane holds (batch=lr, cols cl+16nt+q)
  f32x4 hreg[2];
  #pragma unroll
  for (int nt = 0; nt < 2; ++nt){
    int c = cl + 16*nt;
    hreg[nt] = unpack4(*reinterpret_cast<const bf4*>(aux + AUX_H0 + (b0+lr)*256 + c));
    bf4 hv;
    hv[0]=(short)f2bf(hreg[nt][0]); hv[1]=(short)f2bf(hreg[nt][1]);
    hv[2]=(short)f2bf(hreg[nt][2]); hv[3]=(short)f2bf(hreg[nt][3]);
    *reinterpret_cast<bf4*>(smem + 131072 + lr*512 + (((c>>3) ^ (lr&7)) << 4) + (c&7)*2) = hv;
  }
  __syncthreads();

  // precomputed streaming pointers (loop-carried adds only)
  const ushort_t* wdB = ws16 + ROW_D*256;
  const ushort_t* wdp[4];
  #pragma unroll
  for (int p = 0; p < 4; ++p){
    int pr = ((p&1) ? 256 : 0) + c0 + ((p>>1) ? 16 : 0) + lr;  // mean0,lv0,mean1,lv1
    wdp[p] = wdB + pr*256 + lg*8;
  }
  const ushort_t* apt = Ax    + (size_t)(b0+lr)*1024*768 + cl;
  const ushort_t* ept = eps16 + (size_t)(b0+lr)*1024*256 + cl;
  size_t obase = (size_t)(b0+lr)*262144 + cl;

  for (int t = 0; t < 1024; ++t){
    // packed bf16 loads (issued early, consumed after phase 1 / at sampling)
    bf4 axzp[2], axrp[2], axtp[2], epsp[2];
    #pragma unroll
    for (int nt = 0; nt < 2; ++nt){
      axzp[nt] = *reinterpret_cast<const bf4*>(apt + 16*nt);
      axrp[nt] = *reinterpret_cast<const bf4*>(apt + 256 + 16*nt);
      axtp[nt] = *reinterpret_cast<const bf4*>(apt + 512 + 16*nt);
      epsp[nt] = *reinterpret_cast<const bf4*>(ept + 16*nt);
    }

    // ---- phase 1: z,r,(h@Wth+bth); D = W(A) x h(B)
    f32x4 az[2], ar[2], at[2];
    az[0] = (f32x4){0.f,0.f,0.f,0.f}; az[1] = az[0];
    ar[0] = az[0]; ar[1] = az[0];
    at[0] = unpack4(*reinterpret_cast<const bf4*>(bias_lds + cl));
    at[1] = unpack4(*reinterpret_cast<const bf4*>(bias_lds + cl + 16));
    #pragma unroll
    for (int ks = 0; ks < 8; ++ks){
      int g = ks*4 + lg;
      short8 h = *reinterpret_cast<const short8*>(smem + 131072 + lr*512 + ((g ^ (lr&7)) << 4));
      int nc0 = c0 + lr, nc1 = c0 + 16 + lr;
      short8 th0 = *reinterpret_cast<const short8*>(smem + nc0*512 + ((g ^ (nc0&7)) << 4));
      short8 th1 = *reinterpret_cast<const short8*>(smem + nc1*512 + ((g ^ (nc1&7)) << 4));
      az[0] = MFMA_B16(wzh[0][ks], h, az[0]);  az[1] = MFMA_B16(wzh[1][ks], h, az[1]);
      ar[0] = MFMA_B16(wrh[0][ks], h, ar[0]);  ar[1] = MFMA_B16(wrh[1][ks], h, ar[1]);
      at[0] = MFMA_B16(th0, h, at[0]);         at[1] = MFMA_B16(th1, h, at[1]);
    }

    // prefetch Wd k-steps 0,1 (in flight across barrier, no vmcnt drain)
    short8 wdq[4][2];
    #pragma unroll
    for (int p = 0; p < 4; ++p)
      #pragma unroll
      for (int kk = 0; kk < 2; ++kk)
        wdq[p][kk] = *reinterpret_cast<const short8*>(wdp[p] + kk*32);

    // activations -> h_base (packed b64 into LDS)
    #pragma unroll
    for (int nt = 0; nt < 2; ++nt){
      f32x4 axz = unpack4(axzp[nt]), axr = unpack4(axrp[nt]), axt = unpack4(axtp[nt]);
      bf4 hb4;
      #pragma unroll
      for (int q = 0; q < 4; ++q){
        float zp = az[nt][q] + axz[q];
        float rp = ar[nt][q] + axr[q];
        float zv = 1.f/(1.f + __expf(-zp));
        float rv = 1.f/(1.f + __expf(-rp));
        float tp = axt[q] + rv*at[nt][q];
        float e2 = __expf(-2.f*fabsf(tp));
        float tv = (1.f - e2)/(1.f + e2);
        tv = (tp < 0.f) ? -tv : tv;
        float hb = zv*hreg[nt][q] + (1.f - zv)*tv;
        hb4[q] = (short)f2bf(hb);
      }
      int c = cl + 16*nt;
      *reinterpret_cast<bf4*>(smem + 139264 + lr*512 + (((c>>3) ^ (lr&7)) << 4) + (c&7)*2) = hb4;
    }
    asm volatile("s_waitcnt lgkmcnt(0)" ::: "memory");
    __builtin_amdgcn_s_barrier();
    asm volatile("" ::: "memory");

    // ---- phase 2: params = h_base @ Wd + bd (Wd streamed from L2, 2-deep)
    f32x4 ap4[4];
    ap4[0] = unpack4(*reinterpret_cast<const bf4*>(bias_lds + 256 + cl));
    ap4[1] = unpack4(*reinterpret_cast<const bf4*>(bias_lds + 512 + cl));
    ap4[2] = unpack4(*reinterpret_cast<const bf4*>(bias_lds + 256 + cl + 16));
    ap4[3] = unpack4(*reinterpret_cast<const bf4*>(bias_lds + 512 + cl + 16));
    #pragma unroll
    for (int ks = 0; ks < 8; ++ks){
      int g = ks*4 + lg;
      short8 hb = *reinterpret_cast<const short8*>(smem + 139264 + lr*512 + ((g ^ (lr&7)) << 4));
      short8 w0 = wdq[0][ks&1], w1 = wdq[1][ks&1], w2 = wdq[2][ks&1], w3 = wdq[3][ks&1];
      if (ks < 6){
        #pragma unroll
        for (int p = 0; p < 4; ++p)
          wdq[p][ks&1] = *reinterpret_cast<const short8*>(wdp[p] + (ks+2)*32);
      }
      ap4[0] = MFMA_B16(w0, hb, ap4[0]);
      ap4[1] = MFMA_B16(w1, hb, ap4[1]);
      ap4[2] = MFMA_B16(w2, hb, ap4[2]);
      ap4[3] = MFMA_B16(w3, hb, ap4[3]);
    }

    // ---- sample + write h
    #pragma unroll
    for (int nt = 0; nt < 2; ++nt){
      f32x4 epsv = unpack4(epsp[nt]);
      bf4 s4;
      f32x4 sf;
      #pragma unroll
      for (int q = 0; q < 4; ++q){
        float mean = fminf(fmaxf(ap4[2*nt][q],   -1000.f), 1000.f);
        float lvv  = fminf(fmaxf(ap4[2*nt+1][q], -30.f),   30.f);
        float s = mean + __expf(0.5f*lvv)*epsv[q];
        hreg[nt][q] = s;
        sf[q] = s;
        s4[q] = (short)f2bf(s);
      }
      int c = cl + 16*nt;
      *reinterpret_cast<bf4*>(smem + 131072 + lr*512 + (((c>>3) ^ (lr&7)) << 4) + (c&7)*2) = s4;
      size_t oi = obase + 16*nt;
      if (b16){
        *reinterpret_cast<bf4*>(o16 + oi) = s4;
        if (t == 1023) *reinterpret_cast<bf4*>(o16 + 16777216u + (size_t)(b0+lr)*256 + c) = s4;
      } else {
        *reinterpret_cast<f32x4*>(o32 + oi) = sf;
        if (t == 1023) *reinterpret_cast<f32x4*>(o32 + 16777216u + (size_t)(b0+lr)*256 + c) = sf;
      }
    }
    asm volatile("s_waitcnt lgkmcnt(0)" ::: "memory");
    __builtin_amdgcn_s_barrier();
    asm volatile("" ::: "memory");

    apt += 768; ept += 256; obase += 256;
  }
}

// ---------------------------------------------------------------- host
extern "C" void kernel_launch(void* const* d_in, const int* in_sizes, int n_in,
                              void* d_out, int out_size, void* d_ws, size_t ws_size,
                              hipStream_t stream)
{
  const void* x   = d_in[0];
  const void* h0  = d_in[1];
  const void* eps = d_in[2];
  const void* Wz  = d_in[3];
  const void* bz  = d_in[4];
  const void* Wr  = d_in[5];
  const void* br  = d_in[6];
  const void* Wtx = d_in[7];
  const void* btx = d_in[8];
  const void* Wth = d_in[9];
  const void* bth = d_in[10];
  const void* Wd  = d_in[11];
  const void* bd  = d_in[12];
  ushort_t* ws16 = (ushort_t*)d_ws;
  uint_t* flag = (uint_t*)((char*)d_ws + FLAG_BYTE);
  const ushort_t* aux = ws16 + AUX_OFF;
  ushort_t* Ax = (ushort_t*)((char*)d_ws + AX_OFF_BYTES);
  ushort_t* eps16 = (ushort_t*)((char*)d_ws + EPS_OFF_BYTES);

  detect_kernel<<<dim3(1), dim3(64), 0, stream>>>((const uint_t*)x, flag);
  prep_kernel<<<dim3(2118), dim3(256), 0, stream>>>(Wz, Wr, Wtx, Wth, Wd,
                                                    bz, br, btx, bth, bd, h0,
                                                    flag, ws16);
  epscvt_kernel<<<dim3(8192), dim3(256), 0, stream>>>(eps, flag, eps16);
  xproj_kernel<<<dim3(3072), dim3(256), 0, stream>>>(x, ws16, aux, flag, Ax);

  const int SMEM_REC = 148992;
  (void)hipFuncSetAttribute(reinterpret_cast<const void*>(&gru_kernel),
                            hipFuncAttributeMaxDynamicSharedMemorySize, SMEM_REC);
  gru_kernel<<<dim3(4), dim3(512), SMEM_REC, stream>>>(ws16, Ax, eps16, flag, d_out);
}

// Round 7
// 4506.146 us; speedup vs baseline: 3.6646x; 2.4544x over previous
//
#include <hip/hip_runtime.h>
#include <hip/hip_bf16.h>

typedef unsigned short ushort_t;
typedef unsigned int uint_t;
typedef unsigned long long u64_t;
using f32x4 = __attribute__((ext_vector_type(4))) float;
using bf4 = __attribute__((ext_vector_type(4))) short;
using short8 = __attribute__((ext_vector_type(8))) short;

#define MFMA_B16(a,b,c) __builtin_amdgcn_mfma_f32_16x16x32_bf16((a),(b),(c),0,0,0)
#define MFMA_F8(a,b,c)  __builtin_amdgcn_mfma_f32_16x16x32_fp8_fp8((long)(a),(long)(b),(c),0,0,0)

static __device__ __forceinline__ float bf2f(ushort_t u){
  unsigned v = ((unsigned)u) << 16;
  return __builtin_bit_cast(float, v);
}
static __device__ __forceinline__ ushort_t f2bf(float f){
  __hip_bfloat16 h = __float2bfloat16(f);
  return __builtin_bit_cast(unsigned short, h);
}
static __device__ __forceinline__ f32x4 unpack4(bf4 v){
  f32x4 r;
  r[0]=bf2f((ushort_t)v[0]); r[1]=bf2f((ushort_t)v[1]);
  r[2]=bf2f((ushort_t)v[2]); r[3]=bf2f((ushort_t)v[3]);
  return r;
}
static __device__ __forceinline__ unsigned pack_fp8x4(f32x4 f){
  unsigned u = __builtin_amdgcn_cvt_pk_fp8_f32(f[0], f[1], 0, false);
  u = __builtin_amdgcn_cvt_pk_fp8_f32(f[2], f[3], u, true);
  return u;
}

// ws layout:
//   [0, 524288) elems  : bf16 weights, 2048 rows x 256 k (row-major)
//       rows 0-767: xproj B (Wzx^T|Wrx^T|Wtx^T); 768: Wzh^T; 1024: Wrh^T;
//       1280: Wth^T; 1536-2047: Wd^T (1536-1791 mean, 1792-2047 logvar)
//   [524288, 542208)   : bf16 aux (bz|br|btx|bth|bd|h0)
//   byte 1084416       : uint flag (1 = inputs bf16, 0 = f32)
//   byte 1088512       : fp8 weights: Wrh 64K | Wth 64K | Wd_lv 64K (196608 B)
//   byte 2 MB          : Ax bf16 (65536 x 768)
//   byte 112 MB        : eps bf16 (16777216)
#define W_ELEMS  524288
#define AUX_OFF  524288
#define AUX_BTH  768
#define AUX_BD   1024
#define AUX_H0   1536
#define FLAG_BYTE 1084416u
#define F8_OFF_BYTES  1088512u
#define AX_OFF_BYTES  (2u<<20)
#define EPS_OFF_BYTES (112u<<20)
#define ROW_ZH 768
#define ROW_RH 1024
#define ROW_TH 1280
#define ROW_D  1536

// gru LDS map (bytes)
#define L_WZ    0         // 256 rows x 512 B, swizzled (Wzh^T bf16)
#define L_H16   131072    // 16 x 512 B (h bf16)
#define L_HB16  139264    // 16 x 512 B (h_base bf16)
#define L_H8    147456    // 16 x 256 B (h fp8)
#define L_HB8   151552    // 16 x 256 B (h_base fp8)
#define L_BIAS  155648    // bth[256] | bd[512] bf16
#define SMEM_REC 157184

// ---------------------------------------------------------------- dtype detect
__global__ __launch_bounds__(64) void detect_kernel(const uint_t* __restrict__ x,
                                                    uint_t* __restrict__ flag)
{
  int l = threadIdx.x;
  int cnt = 0;
  for (int i = 0; i < 8; ++i){
    uint_t w = x[i*64 + l];
    uint_t e = (w >> 7) & 0xFF;
    unsigned long long m = __ballot(e >= 100 && e <= 136);
    if (l == 0) cnt += __popcll(m);
  }
  if (l == 0) *flag = (cnt >= 256) ? 1u : 0u;
}

// ---------------------------------------------------------------- prep (canonicalize to bf16)
__global__ __launch_bounds__(256) void prep_kernel(
    const void* __restrict__ Wz, const void* __restrict__ Wr,
    const void* __restrict__ Wtx, const void* __restrict__ Wth,
    const void* __restrict__ Wd,
    const void* __restrict__ bz, const void* __restrict__ br,
    const void* __restrict__ btx, const void* __restrict__ bth,
    const void* __restrict__ bd, const void* __restrict__ h0,
    const uint_t* __restrict__ flag, ushort_t* __restrict__ o)
{
  const bool b16 = (*flag != 0);
  int i = blockIdx.x * 256 + threadIdx.x;          // < 542208
  const void* src; int idx;
  if (i < W_ELEMS){
    int row = i >> 8, k = i & 255;
    if      (row <  256){ src = Wz;  idx = k*256 + row;         }
    else if (row <  512){ src = Wr;  idx = k*256 + (row-256);   }
    else if (row <  768){ src = Wtx; idx = k*256 + (row-512);   }
    else if (row < 1024){ src = Wz;  idx = (256+k)*256 + (row-768);  }
    else if (row < 1280){ src = Wr;  idx = (256+k)*256 + (row-1024); }
    else if (row < 1536){ src = Wth; idx = k*256 + (row-1280);  }
    else                { src = Wd;  idx = k*512 + (row-1536);  }
  } else {
    int j = i - W_ELEMS;
    if      (j <  256){ src = bz;  idx = j;       }
    else if (j <  512){ src = br;  idx = j-256;   }
    else if (j <  768){ src = btx; idx = j-512;   }
    else if (j < 1024){ src = bth; idx = j-768;   }
    else if (j < 1536){ src = bd;  idx = j-1024;  }
    else              { src = h0;  idx = j-1536;  }
  }
  o[i] = b16 ? ((const ushort_t*)src)[idx] : f2bf(((const float*)src)[idx]);
}

// ---------------------------------------------------------------- prep fp8 (Wrh|Wth|Wd_lv)
__global__ __launch_bounds__(256) void prep_f8_kernel(
    const ushort_t* __restrict__ ws, unsigned char* __restrict__ o)
{
  int i = blockIdx.x * 256 + threadIdx.x;          // < 49152, 4 elems each
  int m = i >> 14;                                 // region 0,1,2
  int b = (i & 16383) * 4;                         // byte offset in 64K region
  int row = b >> 8, k = b & 255;
  int srow = (m == 0) ? (ROW_RH + row) : (m == 1) ? (ROW_TH + row) : (ROW_D + 256 + row);
  f32x4 f = unpack4(*reinterpret_cast<const bf4*>(ws + srow*256 + k));
  *reinterpret_cast<unsigned*>(o + (size_t)i*4) = pack_fp8x4(f);
}

// ---------------------------------------------------------------- eps -> bf16
__global__ __launch_bounds__(256) void epscvt_kernel(
    const void* __restrict__ eps, const uint_t* __restrict__ flag,
    ushort_t* __restrict__ o)
{
  const bool b16 = (*flag != 0);
  int i = blockIdx.x * 256 + threadIdx.x;          // 8 elems each, 16777216 total
  if (b16){
    short8 v = reinterpret_cast<const short8*>(eps)[i];
    reinterpret_cast<short8*>(o)[i] = v;
  } else {
    const f32x4* e = reinterpret_cast<const f32x4*>(eps) + i*2;
    f32x4 a = e[0], b = e[1];
    short8 v;
    v[0]=(short)f2bf(a[0]); v[1]=(short)f2bf(a[1]); v[2]=(short)f2bf(a[2]); v[3]=(short)f2bf(a[3]);
    v[4]=(short)f2bf(b[0]); v[5]=(short)f2bf(b[1]); v[6]=(short)f2bf(b[2]); v[7]=(short)f2bf(b[3]);
    reinterpret_cast<short8*>(o)[i] = v;
  }
}

// ---------------------------------------------------------------- x projection GEMM
__global__ __launch_bounds__(256) void xproj_kernel(
    const void* __restrict__ x, const ushort_t* __restrict__ wsB,
    const ushort_t* __restrict__ aux, const uint_t* __restrict__ flag,
    ushort_t* __restrict__ Ax)
{
  __shared__ ushort_t As[32768];
  const bool b16 = (*flag != 0);
  const int tid = threadIdx.x, w = tid >> 6, l = tid & 63, lr = l & 15, lg = l >> 4;
  const int mt = blockIdx.x % 512, nb = blockIdx.x / 512;
  const int m0 = mt * 128, n0 = nb * 128;

  #pragma unroll
  for (int i = 0; i < 16; ++i){
    int gidx = i*256 + tid, row = gidx >> 5, g = gidx & 31;
    short8 v;
    if (b16){
      v = *reinterpret_cast<const short8*>((const ushort_t*)x + (m0+row)*256 + g*8);
    } else {
      const f32x4* xf = reinterpret_cast<const f32x4*>((const float*)x + (m0+row)*256 + g*8);
      f32x4 a0 = xf[0], a1 = xf[1];
      v[0]=(short)f2bf(a0[0]); v[1]=(short)f2bf(a0[1]); v[2]=(short)f2bf(a0[2]); v[3]=(short)f2bf(a0[3]);
      v[4]=(short)f2bf(a1[0]); v[5]=(short)f2bf(a1[1]); v[6]=(short)f2bf(a1[2]); v[7]=(short)f2bf(a1[3]);
    }
    *reinterpret_cast<short8*>(reinterpret_cast<char*>(As) + row*512 + ((g ^ (row&7)) << 4)) = v;
  }
  __syncthreads();

  const int wr = w >> 1, wc = w & 1;
  f32x4 acc[4][4];
  #pragma unroll
  for (int a = 0; a < 4; ++a)
    #pragma unroll
    for (int b = 0; b < 4; ++b) acc[a][b] = (f32x4){0.f,0.f,0.f,0.f};

  #pragma unroll
  for (int ks = 0; ks < 8; ++ks){
    short8 av[4], bv[4];
    #pragma unroll
    for (int mi = 0; mi < 4; ++mi){
      int rT = 64*wr + 16*mi + lr, g = ks*4 + lg;
      av[mi] = *reinterpret_cast<const short8*>(reinterpret_cast<const char*>(As) + rT*512 + ((g ^ (rT&7)) << 4));
    }
    #pragma unroll
    for (int ni = 0; ni < 4; ++ni){
      int nr = n0 + 64*wc + 16*ni + lr;
      bv[ni] = *reinterpret_cast<const short8*>(wsB + nr*256 + ks*32 + lg*8);
    }
    #pragma unroll
    for (int mi = 0; mi < 4; ++mi)
      #pragma unroll
      for (int ni = 0; ni < 4; ++ni)
        acc[mi][ni] = MFMA_B16(av[mi], bv[ni], acc[mi][ni]);
  }

  #pragma unroll
  for (int ni = 0; ni < 4; ++ni){
    int c = n0 + 64*wc + 16*ni + lr;
    float bias = bf2f(aux[c]);
    #pragma unroll
    for (int mi = 0; mi < 4; ++mi)
      #pragma unroll
      for (int j = 0; j < 4; ++j){
        int m = m0 + 64*wr + 16*mi + lg*4 + j;
        Ax[m*768 + c] = f2bf(acc[mi][ni][j] + bias);
      }
  }
}

// ---------------------------------------------------------------- recurrent kernel
// 4 WGs x 512 threads. WG owns batch rows [16*bid,+16); wave w owns cols
// [32w,32w+32). Operand-swapped MFMA: D = W(A) x h(B); lane holds
// (batch = lane&15, cols = 32w + 16nt + (lane>>4)*4 + q).
// ALL weights resident: Wzh bf16 in LDS; Wrh/Wth/Wd_lv fp8 + Wd_mean bf16 in regs.
// Per-step VMEM = Ax (6xb64) + eps (2xb64) only.
__global__ __attribute__((amdgpu_flat_work_group_size(512, 512),
                          amdgpu_waves_per_eu(2, 2)))
void gru_kernel(
    const ushort_t* __restrict__ ws16, const unsigned char* __restrict__ f8w,
    const ushort_t* __restrict__ Ax, const ushort_t* __restrict__ eps16,
    const uint_t* __restrict__ flag, void* __restrict__ outp)
{
  extern __shared__ char smem[];
  const bool b16 = (*flag != 0);
  ushort_t* o16 = (ushort_t*)outp;
  float*    o32 = (float*)outp;
  const ushort_t* aux = ws16 + AUX_OFF;
  ushort_t* bias_lds = (ushort_t*)(smem + L_BIAS);
  const int tid = threadIdx.x, w = tid >> 6, l = tid & 63, lr = l & 15, lg = l >> 4;
  const int b0 = blockIdx.x * 16;
  const int c0 = 32 * w;
  const int cl = c0 + lg*4;                 // lane's col base (nt=0)

  // stage Wzh^T into LDS (swizzled, granule 16B, XOR row&15)
  for (int gi = tid; gi < 8192; gi += 512){
    int row = gi >> 5, g = gi & 31;
    short8 v = *reinterpret_cast<const short8*>(ws16 + (ROW_ZH + row)*256 + g*8);
    *reinterpret_cast<short8*>(smem + row*512 + ((g ^ (row&15)) << 4)) = v;
  }
  if (tid < 256) bias_lds[tid] = aux[AUX_BTH + tid];
  if (tid < 512) bias_lds[256 + tid] = aux[AUX_BD + tid];

  // resident weight fragments
  const unsigned char* f_rh = f8w;
  const unsigned char* f_th = f8w + 65536;
  const unsigned char* f_dl = f8w + 131072;
  u64_t wrh8[2][8], wth8[2][8], wdl8[2][8];
  short8 wdm[2][8];
  #pragma unroll
  for (int nt = 0; nt < 2; ++nt){
    int r = c0 + 16*nt + lr;
    #pragma unroll
    for (int ks = 0; ks < 8; ++ks){
      wrh8[nt][ks] = *reinterpret_cast<const u64_t*>(f_rh + r*256 + ks*32 + lg*8);
      wth8[nt][ks] = *reinterpret_cast<const u64_t*>(f_th + r*256 + ks*32 + lg*8);
      wdl8[nt][ks] = *reinterpret_cast<const u64_t*>(f_dl + r*256 + ks*32 + lg*8);
      wdm[nt][ks]  = *reinterpret_cast<const short8*>(ws16 + (ROW_D + r)*256 + ks*32 + lg*8);
    }
  }

  // h in fp32 regs; lane holds (batch=lr, cols cl+16nt+q)
  f32x4 hreg[2];
  #pragma unroll
  for (int nt = 0; nt < 2; ++nt){
    int c = cl + 16*nt, g = c >> 3;
    hreg[nt] = unpack4(*reinterpret_cast<const bf4*>(aux + AUX_H0 + (b0+lr)*256 + c));
    bf4 hv;
    hv[0]=(short)f2bf(hreg[nt][0]); hv[1]=(short)f2bf(hreg[nt][1]);
    hv[2]=(short)f2bf(hreg[nt][2]); hv[3]=(short)f2bf(hreg[nt][3]);
    *reinterpret_cast<bf4*>(smem + L_H16 + lr*512 + ((g ^ (lr&15)) << 4) + (c&7)*2) = hv;
    *reinterpret_cast<unsigned*>(smem + L_H8 + lr*256 + ((g ^ (lr&15)) << 3) + (c&7)) = pack_fp8x4(hreg[nt]);
  }
  __syncthreads();

  const ushort_t* apt = Ax    + (size_t)(b0+lr)*1024*768 + cl;
  const ushort_t* ept = eps16 + (size_t)(b0+lr)*1024*256 + cl;
  size_t obase = (size_t)(b0+lr)*262144 + cl;

  for (int t = 0; t < 1024; ++t){
    // this step's global loads (only 8), issued up front, consumed late
    bf4 axzp[2], axrp[2], axtp[2], epsp[2];
    #pragma unroll
    for (int nt = 0; nt < 2; ++nt){
      axzp[nt] = *reinterpret_cast<const bf4*>(apt + 16*nt);
      axrp[nt] = *reinterpret_cast<const bf4*>(apt + 256 + 16*nt);
      axtp[nt] = *reinterpret_cast<const bf4*>(apt + 512 + 16*nt);
      epsp[nt] = *reinterpret_cast<const bf4*>(ept + 16*nt);
    }

    // ---- phase 1: z (bf16), r (fp8), h@Wth (fp8)
    f32x4 az[2], ar[2], at[2];
    az[0] = (f32x4){0.f,0.f,0.f,0.f}; az[1] = az[0];
    ar[0] = az[0]; ar[1] = az[0];
    at[0] = unpack4(*reinterpret_cast<const bf4*>(bias_lds + cl));
    at[1] = unpack4(*reinterpret_cast<const bf4*>(bias_lds + cl + 16));
    #pragma unroll
    for (int ks = 0; ks < 8; ++ks){
      const int g = ks*4 + lg;
      short8 hB = *reinterpret_cast<const short8*>(smem + L_H16 + lr*512 + ((g ^ (lr&15)) << 4));
      u64_t  h8 = *reinterpret_cast<const u64_t*>(smem + L_H8 + lr*256 + ((g ^ (lr&15)) << 3));
      int nc0 = c0 + lr, nc1 = c0 + 16 + lr;
      short8 wz0 = *reinterpret_cast<const short8*>(smem + nc0*512 + ((g ^ (nc0&15)) << 4));
      short8 wz1 = *reinterpret_cast<const short8*>(smem + nc1*512 + ((g ^ (nc1&15)) << 4));
      az[0] = MFMA_B16(wz0, hB, az[0]);        az[1] = MFMA_B16(wz1, hB, az[1]);
      ar[0] = MFMA_F8(wrh8[0][ks], h8, ar[0]); ar[1] = MFMA_F8(wrh8[1][ks], h8, ar[1]);
      at[0] = MFMA_F8(wth8[0][ks], h8, at[0]); at[1] = MFMA_F8(wth8[1][ks], h8, at[1]);
    }

    // activations -> h_base (bf16 + fp8 copies into LDS)
    #pragma unroll
    for (int nt = 0; nt < 2; ++nt){
      f32x4 axz = unpack4(axzp[nt]), axr = unpack4(axrp[nt]), axt = unpack4(axtp[nt]);
      f32x4 hb;
      bf4 hb4;
      #pragma unroll
      for (int q = 0; q < 4; ++q){
        float zp = az[nt][q] + axz[q];
        float rp = ar[nt][q] + axr[q];
        float zv = 1.f/(1.f + __expf(-zp));
        float rv = 1.f/(1.f + __expf(-rp));
        float tp = axt[q] + rv*at[nt][q];
        float e2 = __expf(-2.f*fabsf(tp));
        float tv = (1.f - e2)/(1.f + e2);
        tv = (tp < 0.f) ? -tv : tv;
        hb[q] = zv*hreg[nt][q] + (1.f - zv)*tv;
        hb4[q] = (short)f2bf(hb[q]);
      }
      int c = cl + 16*nt, g = c >> 3;
      *reinterpret_cast<bf4*>(smem + L_HB16 + lr*512 + ((g ^ (lr&15)) << 4) + (c&7)*2) = hb4;
      *reinterpret_cast<unsigned*>(smem + L_HB8 + lr*256 + ((g ^ (lr&15)) << 3) + (c&7)) = pack_fp8x4(hb);
    }
    asm volatile("s_waitcnt lgkmcnt(0)" ::: "memory");
    __builtin_amdgcn_s_barrier();
    asm volatile("" ::: "memory");

    // ---- phase 2: mean (bf16, wdm) + logvar (fp8, wdl8) — all resident
    f32x4 apm[2], apl[2];
    apm[0] = unpack4(*reinterpret_cast<const bf4*>(bias_lds + 256 + cl));
    apm[1] = unpack4(*reinterpret_cast<const bf4*>(bias_lds + 256 + cl + 16));
    apl[0] = unpack4(*reinterpret_cast<const bf4*>(bias_lds + 512 + cl));
    apl[1] = unpack4(*reinterpret_cast<const bf4*>(bias_lds + 512 + cl + 16));
    #pragma unroll
    for (int ks = 0; ks < 8; ++ks){
      const int g = ks*4 + lg;
      short8 hbB = *reinterpret_cast<const short8*>(smem + L_HB16 + lr*512 + ((g ^ (lr&15)) << 4));
      u64_t  hb8 = *reinterpret_cast<const u64_t*>(smem + L_HB8 + lr*256 + ((g ^ (lr&15)) << 3));
      apm[0] = MFMA_B16(wdm[0][ks], hbB, apm[0]); apm[1] = MFMA_B16(wdm[1][ks], hbB, apm[1]);
      apl[0] = MFMA_F8(wdl8[0][ks], hb8, apl[0]); apl[1] = MFMA_F8(wdl8[1][ks], hb8, apl[1]);
    }

    // ---- sample + write h
    #pragma unroll
    for (int nt = 0; nt < 2; ++nt){
      f32x4 epsv = unpack4(epsp[nt]);
      bf4 s4;
      f32x4 sf;
      #pragma unroll
      for (int q = 0; q < 4; ++q){
        float mean = fminf(fmaxf(apm[nt][q], -1000.f), 1000.f);
        float lvv  = fminf(fmaxf(apl[nt][q], -30.f),   30.f);
        float s = mean + __expf(0.5f*lvv)*epsv[q];
        hreg[nt][q] = s;
        sf[q] = s;
        s4[q] = (short)f2bf(s);
      }
      int c = cl + 16*nt, g = c >> 3;
      *reinterpret_cast<bf4*>(smem + L_H16 + lr*512 + ((g ^ (lr&15)) << 4) + (c&7)*2) = s4;
      *reinterpret_cast<unsigned*>(smem + L_H8 + lr*256 + ((g ^ (lr&15)) << 3) + (c&7)) = pack_fp8x4(sf);
      size_t oi = obase + 16*nt;
      if (b16){
        *reinterpret_cast<bf4*>(o16 + oi) = s4;
        if (t == 1023) *reinterpret_cast<bf4*>(o16 + 16777216u + (size_t)(b0+lr)*256 + c) = s4;
      } else {
        *reinterpret_cast<f32x4*>(o32 + oi) = sf;
        if (t == 1023) *reinterpret_cast<f32x4*>(o32 + 16777216u + (size_t)(b0+lr)*256 + c) = sf;
      }
    }
    asm volatile("s_waitcnt lgkmcnt(0)" ::: "memory");
    __builtin_amdgcn_s_barrier();
    asm volatile("" ::: "memory");

    apt += 768; ept += 256; obase += 256;
  }
}

// ---------------------------------------------------------------- host
extern "C" void kernel_launch(void* const* d_in, const int* in_sizes, int n_in,
                              void* d_out, int out_size, void* d_ws, size_t ws_size,
                              hipStream_t stream)
{
  const void* x   = d_in[0];
  const void* h0  = d_in[1];
  const void* eps = d_in[2];
  const void* Wz  = d_in[3];
  const void* bz  = d_in[4];
  const void* Wr  = d_in[5];
  const void* br  = d_in[6];
  const void* Wtx = d_in[7];
  const void* btx = d_in[8];
  const void* Wth = d_in[9];
  const void* bth = d_in[10];
  const void* Wd  = d_in[11];
  const void* bd  = d_in[12];
  ushort_t* ws16 = (ushort_t*)d_ws;
  uint_t* flag = (uint_t*)((char*)d_ws + FLAG_BYTE);
  const ushort_t* aux = ws16 + AUX_OFF;
  unsigned char* f8w = (unsigned char*)d_ws + F8_OFF_BYTES;
  ushort_t* Ax = (ushort_t*)((char*)d_ws + AX_OFF_BYTES);
  ushort_t* eps16 = (ushort_t*)((char*)d_ws + EPS_OFF_BYTES);

  detect_kernel<<<dim3(1), dim3(64), 0, stream>>>((const uint_t*)x, flag);
  prep_kernel<<<dim3(2118), dim3(256), 0, stream>>>(Wz, Wr, Wtx, Wth, Wd,
                                                    bz, br, btx, bth, bd, h0,
                                                    flag, ws16);
  prep_f8_kernel<<<dim3(192), dim3(256), 0, stream>>>(ws16, f8w);
  epscvt_kernel<<<dim3(8192), dim3(256), 0, stream>>>(eps, flag, eps16);
  xproj_kernel<<<dim3(3072), dim3(256), 0, stream>>>(x, ws16, aux, flag, Ax);

  (void)hipFuncSetAttribute(reinterpret_cast<const void*>(&gru_kernel),
                            hipFuncAttributeMaxDynamicSharedMemorySize, SMEM_REC);
  gru_kernel<<<dim3(4), dim3(512), SMEM_REC, stream>>>(ws16, f8w, Ax, eps16, flag, d_out);
}